// Round 2
// baseline (53.272 us; speedup 1.0000x reference)
//
#include <hip/hip_runtime.h>

// CombinePatches: col2im/fold of 4x4x4 stride-2 volume patches + divide by
// overlap count, gather-formulated (each patch element feeds exactly one
// output voxel). Round 2: one thread per (b,d,h, w-PAIR). The even/odd voxel
// of a pair read ADJACENT float4s in the same patch slot:
//   acc_even += P[zw=q][i][j][l=0] + P[zw=q-1][i][j][l=2]
//   acc_odd  += P[zw=q][i][j][l=1] + P[zw=q-1][i][j][l=3]
// -> two contiguous 32B reads per (i,j) instead of four scattered 16B reads.
// Wave (64 lanes) spans exactly the q axis, so zd/zh bounds checks are
// wave-uniform; only q=0 / q=63 lanes predicate their loads.
// Count is separable: cnt = ci*cj*cl in {1,2,4,8} -> exact fp32 reciprocal.

constexpr int OD = 31, OH = 63, OW = 63;   // patch grid
// out: [2,64,128,128,4] f32 ; patches: [2,31,63,63,256] f32 (64 float4/patch)

using f4 = __attribute__((ext_vector_type(4))) float;

__global__ __launch_bounds__(256) void fold_pair_kernel(
    const f4* __restrict__ p, f4* __restrict__ out)
{
    int t = blockIdx.x * 256 + threadIdx.x;   // 2^20 threads total
    int q = t & 63;                           // w = 2q, 2q+1
    int h = (t >> 6) & 127;
    int d = (t >> 13) & 63;
    int b = t >> 19;

    const int i0 = d & 1, j0 = h & 1;
    const int zdA = (d - i0) >> 1;            // zd for i=i0 ; zdA-1 for i=i0+2
    const int zhA = (h - j0) >> 1;

    const int ci = (zdA <= OD - 1) + (zdA >= 1);
    const int cj = (zhA <= OH - 1) + (zhA >= 1);
    const int cl = (q   <= OW - 1) + (q   >= 1);
    const float inv = 1.0f / (float)(ci * cj * cl);   // {1..8}: exact

    const bool qhi = (q <= OW - 1);           // patch zw=q   valid
    const bool qlo = (q >= 1);                // patch zw=q-1 valid

    f4 ae = (f4)0.0f, ao = (f4)0.0f;

    #pragma unroll
    for (int ii = 0; ii < 2; ++ii) {
        const int zd = zdA - ii;
        if ((unsigned)zd > (unsigned)(OD - 1)) continue;   // wave-uniform
        const int i = i0 + 2 * ii;
        #pragma unroll
        for (int jj = 0; jj < 2; ++jj) {
            const int zh = zhA - jj;
            if ((unsigned)zh > (unsigned)(OH - 1)) continue;  // wave-uniform
            const int j = j0 + 2 * jj;
            const int rowbase = (((b * OD + zd) * OH + zh) * OW) << 6; // *64 f4
            const int koff = (i << 4) + (j << 2);
            if (qhi) {
                const f4* s = p + rowbase + (q << 6) + koff;   // l=0,1
                ae += s[0];
                ao += s[1];
            }
            if (qlo) {
                const f4* s = p + rowbase + ((q - 1) << 6) + koff + 2; // l=2,3
                ae += s[0];
                ao += s[1];
            }
        }
    }

    ae *= inv;
    ao *= inv;

    const int n = ((t >> 6) << 7) + (q << 1);   // float4 index into out
    __builtin_nontemporal_store(ae, &out[n]);
    __builtin_nontemporal_store(ao, &out[n + 1]);
}

extern "C" void kernel_launch(void* const* d_in, const int* in_sizes, int n_in,
                              void* d_out, int out_size, void* d_ws, size_t ws_size,
                              hipStream_t stream)
{
    const f4* patches = (const f4*)d_in[0];   // [2,31,63,63,256] f32
    f4* out = (f4*)d_out;                     // [2,64,128,128,4] f32

    const int total_pairs = 2 * 64 * 128 * 64;       // 2^20
    fold_pair_kernel<<<total_pairs / 256, 256, 0, stream>>>(patches, out);
}